// Round 12
// baseline (685.421 us; speedup 1.0000x reference)
//
#include <hip/hip_runtime.h>

#define TS 256
#define BB 256
#define ED 256
#define HD 512

typedef __bf16 bf16_t;
typedef bf16_t bf16x8 __attribute__((ext_vector_type(8)));
typedef float f32x16 __attribute__((ext_vector_type(16)));
typedef float f32x4_t __attribute__((ext_vector_type(4)));
typedef float f32x2_t __attribute__((ext_vector_type(2)));
typedef unsigned short u16x8 __attribute__((ext_vector_type(8)));
typedef int i32x4 __attribute__((ext_vector_type(4)));
typedef int i32x2 __attribute__((ext_vector_type(2)));

// workspace layout (bytes)
// tagged h: dword = [tag16 | bf16]; chunk (16 units) = 64 lanes x 8 dwords = 2KB
#define HGRP_BYTES 65536                  // per-group tagged h (32 chunks x 2KB)
#define HBUF_BYTES 524288                 // x8 groups, one double-buffer half
#define EBUF_OFF   1048576                // bf16 embedding table [512][256] (256KB)

// LDS layout (bytes)
#define L_AE   0        // wave-private e-tiles: [4 waves][32 rows][128B], XOR-swizzled
#define L_PB   16384    // partials, double-buffered: [2][4 waves][64 cols][36 f32]
#define L_BIAS 90112    // 64 f32
#define L_TOT  90368    // >80KB -> 1 block/CU (co-residency guarantee)

__device__ __forceinline__ unsigned short f2bf(float f) {
  unsigned u = __builtin_bit_cast(unsigned, f);
  u += 0x7FFFu + ((u >> 16) & 1u);     // RNE
  return (unsigned short)(u >> 16);
}
__device__ __forceinline__ float sigm(float x) {
  return __builtin_amdgcn_rcpf(1.f + __expf(-x));
}
__device__ __forceinline__ float tanhf_(float x) {
  return 1.f - 2.f * __builtin_amdgcn_rcpf(1.f + __expf(2.f * x));
}

// ---- device-scope (sc1) ops: write-through to / load from device coherence point ----
__device__ __forceinline__ void store_sc1_x2(void* p, i32x2 v) {
  asm volatile("global_store_dwordx2 %0, %1, off sc1" :: "v"(p), "v"(v) : "memory");
}
__device__ __forceinline__ i32x4 load_sc1_x4_issue(const void* p) {
  i32x4 r;
  asm volatile("global_load_dwordx4 %0, %1, off sc1" : "=v"(r) : "v"(p) : "memory");
  return r;
}
__device__ __forceinline__ int load_sc1_dw_wait(const void* p) {
  int r;
  asm volatile("global_load_dword %0, %1, off sc1\n\ts_waitcnt vmcnt(0)"
               : "=v"(r) : "v"(p) : "memory");
  return r;
}
__device__ __forceinline__ void fence_vm() {
  asm volatile("s_waitcnt vmcnt(0)" ::: "memory");
}
__device__ __forceinline__ void fence_vm8() {
  asm volatile("s_waitcnt vmcnt(8)" ::: "memory");
}

__global__ void emb2bf_kernel(const float* __restrict__ emb,
                              unsigned short* __restrict__ ebuf) {
  int i = blockIdx.x * 256 + threadIdx.x;   // 512*256 elements
  ebuf[i] = f2bf(emb[i]);
}

__global__ __launch_bounds__(256, 1) void lstm_kernel(
    const int* __restrict__ xs, const float* __restrict__ Wih,
    const float* __restrict__ Whh, const float* __restrict__ bih,
    const float* __restrict__ bhh, char* __restrict__ ws,
    float* __restrict__ out)
{
  __shared__ __align__(128) char lds[L_TOT];
  const int tid  = threadIdx.x;
  const int lane = tid & 63;
  const int wv   = tid >> 6;          // wave 0..3 (K-split)
  const int bg   = blockIdx.x & 7;    // batch group (placement-independent)
  const int gt   = blockIdx.x >> 3;   // gate tile (units gt*16..+16)

  const char* ebuf = ws + EBUF_OFF;

  // ---- persistent weight fragments in VGPRs (bf16), K split across waves ----
  bf16x8 be[4][2], bhf[8][2];
  {
    const int kl = (lane >> 5) << 3;
    #pragma unroll
    for (int nt = 0; nt < 2; ++nt) {
      const int col = nt*32 + (lane & 31);                 // local gate col 0..63
      const int gr  = (col >> 4)*HD + gt*16 + (col & 15);  // global gate row
      const float* wa = Wih + (size_t)gr * ED;
      const float* wb = Whh + (size_t)gr * HD;
      #pragma unroll
      for (int ks = 0; ks < 4; ++ks) {
        u16x8 tmp;
        #pragma unroll
        for (int j = 0; j < 8; ++j) tmp[j] = f2bf(wa[64*wv + 16*ks + kl + j]);
        be[ks][nt] = __builtin_bit_cast(bf16x8, tmp);
      }
      #pragma unroll
      for (int ks = 0; ks < 8; ++ks) {
        u16x8 tmp;
        #pragma unroll
        for (int j = 0; j < 8; ++j) tmp[j] = f2bf(wb[128*wv + 16*ks + kl + j]);
        bhf[ks][nt] = __builtin_bit_cast(bf16x8, tmp);
      }
    }
  }
  if (tid < 64) {
    const int gr = (tid >> 4)*HD + gt*16 + (tid & 15);
    *(float*)(lds + L_BIAS + tid*4) = bih[gr] + bhh[gr];
  }

  // epilogue thread mapping: row e_rr, unit pair (cu, cu+1), cu = e_hi*8+2*e_jj
  const int e_hi = tid >> 7, e_rr = (tid >> 2) & 31, e_jj = tid & 3;
  const int cu   = e_hi*8 + 2*e_jj;
  float cr0 = 0.f, cr1 = 0.f;

  // ---- stage wave-private Ae for t=0: wave wv holds e-cols [64wv,+64) ----
  {
    i32x4 aev[4];
    #pragma unroll
    for (int i = 0; i < 4; ++i) {
      const int ck = i*64 + lane;            // 0..255
      const int row = ck >> 3, c8 = ck & 7;
      const int xv = xs[bg*32 + row];
      aev[i] = *(const i32x4*)(ebuf + xv*512 + wv*128 + c8*16);
    }
    #pragma unroll
    for (int i = 0; i < 4; ++i) {
      const int ck = i*64 + lane;
      const int row = ck >> 3, c8 = ck & 7;
      *(i32x4*)(lds + L_AE + wv*4096 + row*128 + ((c8*16) ^ ((row & 7) << 4))) = aev[i];
    }
  }
  // no barrier: L_AE wave-private; L_BIAS consumed only after B2(t=0)

  for (int t = 0; t < TS; ++t) {
    const int p = t & 1;   // read h_{t-1} (tag t) from buf p; write h_t (tag t+1) to p^1
    const char* hsrc = ws + p*HBUF_BYTES + bg*HGRP_BYTES;

    // ---- 1. e-part MFMA first (gives producer stores time to reach MALL) ----
    f32x16 acc0 = {}, acc1 = {};
    #pragma unroll
    for (int ks = 0; ks < 4; ++ks) {
      const int row = lane & 31;
      const int koff = 32*ks + ((lane >> 5) << 4);
      bf16x8 a = *(const bf16x8*)(lds + L_AE + wv*4096 + row*128 +
                                  (koff ^ ((row & 7) << 4)));
      acc0 = __builtin_amdgcn_mfma_f32_32x32x16_bf16(a, be[ks][0], acc0, 0, 0, 0);
      acc1 = __builtin_amdgcn_mfma_f32_32x32x16_bf16(a, be[ks][1], acc1, 0, 0, 0);
    }

    // ---- 2. issue tagged h loads (chunks wv*8..+8, issue order ks=0..7) ----
    i32x4 hv[16];
    #pragma unroll
    for (int ks = 0; ks < 8; ++ks) {
      const char* a = hsrc + ((wv*8 + ks)*64 + lane)*32;
      hv[ks*2]     = load_sc1_x4_issue(a);
      hv[ks*2 + 1] = load_sc1_x4_issue(a + 16);
    }

    // ---- 3. staged verify + consume-as-ready; direct retries, then sentinel ----
    {
      const int tw = t << 16;
      unsigned done = 0;

      // VC(ks): verify chunk ks; if wave-uniformly valid, unpack + 2 MFMAs
      #define VC(ksc) do { if (!(done & (1u << (ksc)))) {                        \
        const i32x4 lo = hv[(ksc)*2], hh = hv[(ksc)*2 + 1];                      \
        int bad = (lo.x^tw)|(lo.y^tw)|(lo.z^tw)|(lo.w^tw)|                       \
                  (hh.x^tw)|(hh.y^tw)|(hh.z^tw)|(hh.w^tw);                       \
        if (__all((((unsigned)bad) >> 16) == 0)) {                               \
          i32x4 pk;                                                              \
          pk.x = __builtin_amdgcn_perm((unsigned)lo.y,(unsigned)lo.x,0x05040100u);\
          pk.y = __builtin_amdgcn_perm((unsigned)lo.w,(unsigned)lo.z,0x05040100u);\
          pk.z = __builtin_amdgcn_perm((unsigned)hh.y,(unsigned)hh.x,0x05040100u);\
          pk.w = __builtin_amdgcn_perm((unsigned)hh.w,(unsigned)hh.z,0x05040100u);\
          bf16x8 aa = __builtin_bit_cast(bf16x8, pk);                            \
          acc0 = __builtin_amdgcn_mfma_f32_32x32x16_bf16(aa, bhf[(ksc)][0], acc0, 0,0,0); \
          acc1 = __builtin_amdgcn_mfma_f32_32x32x16_bf16(aa, bhf[(ksc)][1], acc1, 0,0,0); \
          done |= (1u << (ksc));                                                 \
        } } } while (0)

      #define RELOAD_MISSING do {                                                \
        _Pragma("unroll")                                                        \
        for (int ks = 0; ks < 8; ++ks) {                                         \
          if (!(done & (1u << ks))) {                                            \
            const char* a = hsrc + ((wv*8 + ks)*64 + lane)*32;                   \
            hv[ks*2]     = load_sc1_x4_issue(a);                                 \
            hv[ks*2 + 1] = load_sc1_x4_issue(a + 16);                            \
          }                                                                      \
        }                                                                        \
        fence_vm();                                                              \
        __builtin_amdgcn_sched_barrier(0);                                       \
      } while (0)

      // hit path: vmcnt retires in issue order; <=2 prior stores in flight, so
      // vmcnt(8) guarantees the first 8 loads (chunks 0-3) have landed.
      fence_vm8();
      __builtin_amdgcn_sched_barrier(0);
      VC(0); VC(1); VC(2); VC(3);
      fence_vm();
      __builtin_amdgcn_sched_barrier(0);
      VC(4); VC(5); VC(6); VC(7);

      // direct retries (no sentinel): each self-throttled by its vmcnt(0) RT,
      // reloads ONLY stale chunks (2-4KB typical) -> no load storm possible.
      if (done != 0xFFu) {
        RELOAD_MISSING;
        VC(0); VC(1); VC(2); VC(3); VC(4); VC(5); VC(6); VC(7);
      }
      if (done != 0xFFu) {
        RELOAD_MISSING;
        VC(0); VC(1); VC(2); VC(3); VC(4); VC(5); VC(6); VC(7);
      }

      // fallback: R11-proven sentinel-throttled loop (liveness guarantee)
      int it = 0;
      while (done != 0xFFu) {
        if (++it > (1 << 15)) break;               // safety valve
        for (;;) {
          int v = tw;
          if (lane < 8 && !(done & (1u << lane)))
            v = load_sc1_dw_wait(hsrc + (wv*8 + lane)*2048);
          if (__all((((unsigned)(v ^ tw)) >> 16) == 0)) break;
          if (++it > (1 << 15)) break;
        }
        if (it > (1 << 15)) break;
        RELOAD_MISSING;
        VC(0); VC(1); VC(2); VC(3); VC(4); VC(5); VC(6); VC(7);
      }
      #undef RELOAD_MISSING
      #undef VC
    }

    // ---- K-split partials, double-buffered col-major [t&1][wv][col][36] ----
    {
      const int c0 = lane & 31, hi4 = (lane >> 5) << 2;
      char* pb = lds + L_PB + p*36864 + wv*9216;
      #pragma unroll
      for (int q = 0; q < 4; ++q) {
        const int r0 = q*8 + hi4;
        f32x4_t v0 = {acc0[q*4], acc0[q*4+1], acc0[q*4+2], acc0[q*4+3]};
        f32x4_t v1 = {acc1[q*4], acc1[q*4+1], acc1[q*4+2], acc1[q*4+3]};
        *(f32x4_t*)(pb + (c0*36 + r0)*4)        = v0;
        *(f32x4_t*)(pb + ((32 + c0)*36 + r0)*4) = v1;
      }
    }
    __syncthreads();   // B2 — the only barrier per step

    // ---- issue next-step embedding gather (overlaps epilogue LDS reads) ----
    i32x4 aev[4];
    if (t < TS-1) {
      #pragma unroll
      for (int i = 0; i < 4; ++i) {
        const int ck = i*64 + lane;
        const int row = ck >> 3, c8 = ck & 7;
        const int xv = xs[(t+1)*BB + bg*32 + row];
        aev[i] = *(const i32x4*)(ebuf + xv*512 + wv*128 + c8*16);
      }
    }

    // ---- fused epilogue: reduce + activations + c/h ----
    float h0, h1;
    {
      const char* pbb = lds + L_PB + p*36864;
      float a8[8];
      #pragma unroll
      for (int g = 0; g < 4; ++g) {
        f32x2_t bv = *(const f32x2_t*)(lds + L_BIAS + (g*16 + cu)*4);
        float s0 = bv[0], s1 = bv[1];
        #pragma unroll
        for (int pp = 0; pp < 4; ++pp) {
          const char* q = pbb + pp*9216 + ((g*16 + cu)*36 + e_rr)*4;
          s0 += *(const float*)(q);
          s1 += *(const float*)(q + 36*4);
        }
        a8[g*2] = s0; a8[g*2+1] = s1;
      }
      const float i0 = sigm(a8[0]),   i1 = sigm(a8[1]);
      const float f0 = sigm(a8[2]),   f1 = sigm(a8[3]);
      const float g0 = tanhf_(a8[4]), g1 = tanhf_(a8[5]);
      const float o0 = sigm(a8[6]),   o1 = sigm(a8[7]);
      cr0 = f0*cr0 + i0*g0;
      cr1 = f1*cr1 + i1*g1;
      h0 = o0 * tanhf_(cr0);
      h1 = o1 * tanhf_(cr1);
    }

    // ---- tagged h store FIRST (fire-and-forget, self-validating), then outs ----
    if (t < TS-1) {
      const int tagw = (t + 1) << 16;
      i32x2 d = { tagw | (int)f2bf(h0), tagw | (int)f2bf(h1) };
      store_sc1_x2(ws + (p^1)*HBUF_BYTES + bg*HGRP_BYTES +
                   (gt*64 + e_hi*32 + e_rr)*32 + e_jj*8, d);
    }
    {
      float* orow = out + ((size_t)t*BB + bg*32 + e_rr)*HD + gt*16 + cu;
      *(f32x2_t*)orow = (f32x2_t){h0, h1};
      if (t == TS-1) {
        float* ho = out + (size_t)TS*BB*HD + (size_t)(bg*32 + e_rr)*HD + gt*16 + cu;
        *(f32x2_t*)ho = (f32x2_t){h0, h1};
        float* cb = ho + BB*HD;
        *(f32x2_t*)cb = (f32x2_t){cr0, cr1};
      }
    }

    // ---- wave-private L_AE staging for t+1 (no barrier needed) ----
    if (t < TS-1) {
      #pragma unroll
      for (int i = 0; i < 4; ++i) {
        const int ck = i*64 + lane;
        const int row = ck >> 3, c8 = ck & 7;
        *(i32x4*)(lds + L_AE + wv*4096 + row*128 + ((c8*16) ^ ((row & 7) << 4))) = aev[i];
      }
    }
  }
}

extern "C" void kernel_launch(void* const* d_in, const int* in_sizes, int n_in,
                              void* d_out, int out_size, void* d_ws, size_t ws_size,
                              hipStream_t stream) {
  (void)in_sizes; (void)n_in; (void)out_size; (void)ws_size;
  const int*   xs  = (const int*)d_in[0];
  const float* emb = (const float*)d_in[1];
  const float* Wih = (const float*)d_in[2];
  const float* Whh = (const float*)d_in[3];
  const float* bih = (const float*)d_in[4];
  const float* bhh = (const float*)d_in[5];
  char* ws = (char*)d_ws;

  // deterministic per-call init: buf0 = h_{-1}=0 with tag 0
  (void)hipMemsetAsync(ws, 0, HBUF_BYTES, stream);
  emb2bf_kernel<<<512, 256, 0, stream>>>(emb, (unsigned short*)(ws + EBUF_OFF));
  lstm_kernel<<<256, 256, 0, stream>>>(xs, Wih, Whh, bih, bhh, ws, (float*)d_out);
}

// Round 13
// 601.510 us; speedup vs baseline: 1.1395x; 1.1395x over previous
//
#include <hip/hip_runtime.h>

#define TS 256
#define BB 256
#define ED 256
#define HD 512

typedef __bf16 bf16_t;
typedef bf16_t bf16x8 __attribute__((ext_vector_type(8)));
typedef float f32x16 __attribute__((ext_vector_type(16)));
typedef float f32x4_t __attribute__((ext_vector_type(4)));
typedef float f32x2_t __attribute__((ext_vector_type(2)));
typedef unsigned short u16x8 __attribute__((ext_vector_type(8)));
typedef int i32x4 __attribute__((ext_vector_type(4)));
typedef int i32x2 __attribute__((ext_vector_type(2)));

// workspace layout (bytes)
// tagged h: dword = [tag16 | bf16]; chunk (16 units) = 64 lanes x 8 dwords = 2KB
#define HGRP_BYTES 65536                  // per-group tagged h (32 chunks x 2KB)
#define HBUF_BYTES 524288                 // x8 groups, one double-buffer half
#define EBUF_OFF   1048576                // bf16 embedding table [512][256] (256KB)

// LDS layout (bytes)
#define L_AE   0        // wave-private e-tiles: [4 waves][32 rows][128B], XOR-swizzled
#define L_PB   16384    // partials, double-buffered: [2][4 waves][64 cols][36 f32]
#define L_BIAS 90112    // 64 f32
#define L_TOT  90368    // >80KB -> 1 block/CU (co-residency guarantee)

__device__ __forceinline__ unsigned short f2bf(float f) {
  unsigned u = __builtin_bit_cast(unsigned, f);
  u += 0x7FFFu + ((u >> 16) & 1u);     // RNE
  return (unsigned short)(u >> 16);
}
__device__ __forceinline__ float sigm(float x) {
  return __builtin_amdgcn_rcpf(1.f + __expf(-x));
}
__device__ __forceinline__ float tanhf_(float x) {
  return 1.f - 2.f * __builtin_amdgcn_rcpf(1.f + __expf(2.f * x));
}

// ---- memory ops ----
// sc1: device coherence point (authoritative, cross-XCD). sc0: bypass L1, may
// hit own XCD L2 -- fast path only; tags + generation spacing make stale safe.
__device__ __forceinline__ void store_sc1_x2(void* p, i32x2 v) {
  asm volatile("global_store_dwordx2 %0, %1, off sc1" :: "v"(p), "v"(v) : "memory");
}
__device__ __forceinline__ i32x4 load_sc1_x4_issue(const void* p) {
  i32x4 r;
  asm volatile("global_load_dwordx4 %0, %1, off sc1" : "=v"(r) : "v"(p) : "memory");
  return r;
}
__device__ __forceinline__ i32x4 load_sc0_x4_issue(const void* p) {
  i32x4 r;
  asm volatile("global_load_dwordx4 %0, %1, off sc0" : "=v"(r) : "v"(p) : "memory");
  return r;
}
__device__ __forceinline__ int load_sc1_dw_wait(const void* p) {
  int r;
  asm volatile("global_load_dword %0, %1, off sc1\n\ts_waitcnt vmcnt(0)"
               : "=v"(r) : "v"(p) : "memory");
  return r;
}
__device__ __forceinline__ void fence_vm() {
  asm volatile("s_waitcnt vmcnt(0)" ::: "memory");
}
__device__ __forceinline__ void fence_vm8() {
  asm volatile("s_waitcnt vmcnt(8)" ::: "memory");
}

__global__ void emb2bf_kernel(const float* __restrict__ emb,
                              unsigned short* __restrict__ ebuf) {
  int i = blockIdx.x * 256 + threadIdx.x;   // 512*256 elements
  ebuf[i] = f2bf(emb[i]);
}

__global__ __launch_bounds__(256, 1) void lstm_kernel(
    const int* __restrict__ xs, const float* __restrict__ Wih,
    const float* __restrict__ Whh, const float* __restrict__ bih,
    const float* __restrict__ bhh, char* __restrict__ ws,
    float* __restrict__ out)
{
  __shared__ __align__(128) char lds[L_TOT];
  const int tid  = threadIdx.x;
  const int lane = tid & 63;
  const int wv   = tid >> 6;          // wave 0..3 (K-split)
  const int bg   = blockIdx.x & 7;    // batch group (placement-independent)
  const int gt   = blockIdx.x >> 3;   // gate tile (units gt*16..+16)

  const char* ebuf = ws + EBUF_OFF;

  // ---- persistent weight fragments in VGPRs (bf16), K split across waves ----
  bf16x8 be[4][2], bhf[8][2];
  {
    const int kl = (lane >> 5) << 3;
    #pragma unroll
    for (int nt = 0; nt < 2; ++nt) {
      const int col = nt*32 + (lane & 31);                 // local gate col 0..63
      const int gr  = (col >> 4)*HD + gt*16 + (col & 15);  // global gate row
      const float* wa = Wih + (size_t)gr * ED;
      const float* wb = Whh + (size_t)gr * HD;
      #pragma unroll
      for (int ks = 0; ks < 4; ++ks) {
        u16x8 tmp;
        #pragma unroll
        for (int j = 0; j < 8; ++j) tmp[j] = f2bf(wa[64*wv + 16*ks + kl + j]);
        be[ks][nt] = __builtin_bit_cast(bf16x8, tmp);
      }
      #pragma unroll
      for (int ks = 0; ks < 8; ++ks) {
        u16x8 tmp;
        #pragma unroll
        for (int j = 0; j < 8; ++j) tmp[j] = f2bf(wb[128*wv + 16*ks + kl + j]);
        bhf[ks][nt] = __builtin_bit_cast(bf16x8, tmp);
      }
    }
  }
  if (tid < 64) {
    const int gr = (tid >> 4)*HD + gt*16 + (tid & 15);
    *(float*)(lds + L_BIAS + tid*4) = bih[gr] + bhh[gr];
  }

  // epilogue thread mapping: row e_rr, unit pair (cu, cu+1), cu = e_hi*8+2*e_jj
  const int e_hi = tid >> 7, e_rr = (tid >> 2) & 31, e_jj = tid & 3;
  const int cu   = e_hi*8 + 2*e_jj;
  float cr0 = 0.f, cr1 = 0.f;

  // ---- stage wave-private Ae for t=0: wave wv holds e-cols [64wv,+64) ----
  {
    i32x4 aev[4];
    #pragma unroll
    for (int i = 0; i < 4; ++i) {
      const int ck = i*64 + lane;            // 0..255
      const int row = ck >> 3, c8 = ck & 7;
      const int xv = xs[bg*32 + row];
      aev[i] = *(const i32x4*)(ebuf + xv*512 + wv*128 + c8*16);
    }
    #pragma unroll
    for (int i = 0; i < 4; ++i) {
      const int ck = i*64 + lane;
      const int row = ck >> 3, c8 = ck & 7;
      *(i32x4*)(lds + L_AE + wv*4096 + row*128 + ((c8*16) ^ ((row & 7) << 4))) = aev[i];
    }
  }
  // no barrier: L_AE wave-private; L_BIAS consumed only after B2(t=0)

  for (int t = 0; t < TS; ++t) {
    const int p = t & 1;   // read h_{t-1} (tag t) from buf p; write h_t (tag t+1) to p^1
    const char* hsrc = ws + p*HBUF_BYTES + bg*HGRP_BYTES;

    // ---- 1. e-part MFMA first (gives producer stores time to reach L2/MALL) ----
    f32x16 acc0 = {}, acc1 = {};
    #pragma unroll
    for (int ks = 0; ks < 4; ++ks) {
      const int row = lane & 31;
      const int koff = 32*ks + ((lane >> 5) << 4);
      bf16x8 a = *(const bf16x8*)(lds + L_AE + wv*4096 + row*128 +
                                  (koff ^ ((row & 7) << 4)));
      acc0 = __builtin_amdgcn_mfma_f32_32x32x16_bf16(a, be[ks][0], acc0, 0, 0, 0);
      acc1 = __builtin_amdgcn_mfma_f32_32x32x16_bf16(a, be[ks][1], acc1, 0, 0, 0);
    }

    // ---- 2. issue tagged h loads, sc0 FAST PATH (may hit own-XCD L2 fresh;
    // ----    stale lines carry tag <= t-2 and are caught by the verify) ----
    i32x4 hv[16];
    #pragma unroll
    for (int ks = 0; ks < 8; ++ks) {
      const char* a = hsrc + ((wv*8 + ks)*64 + lane)*32;
      hv[ks*2]     = load_sc0_x4_issue(a);
      hv[ks*2 + 1] = load_sc0_x4_issue(a + 16);
    }

    // ---- 3. staged verify + consume-as-ready; sc1 retries, then sentinel ----
    {
      const int tw = t << 16;
      unsigned done = 0;

      // VC(ks): verify chunk ks; if wave-uniformly valid, unpack + 2 MFMAs
      #define VC(ksc) do { if (!(done & (1u << (ksc)))) {                        \
        const i32x4 lo = hv[(ksc)*2], hh = hv[(ksc)*2 + 1];                      \
        int bad = (lo.x^tw)|(lo.y^tw)|(lo.z^tw)|(lo.w^tw)|                       \
                  (hh.x^tw)|(hh.y^tw)|(hh.z^tw)|(hh.w^tw);                       \
        if (__all((((unsigned)bad) >> 16) == 0)) {                               \
          i32x4 pk;                                                              \
          pk.x = __builtin_amdgcn_perm((unsigned)lo.y,(unsigned)lo.x,0x05040100u);\
          pk.y = __builtin_amdgcn_perm((unsigned)lo.w,(unsigned)lo.z,0x05040100u);\
          pk.z = __builtin_amdgcn_perm((unsigned)hh.y,(unsigned)hh.x,0x05040100u);\
          pk.w = __builtin_amdgcn_perm((unsigned)hh.w,(unsigned)hh.z,0x05040100u);\
          bf16x8 aa = __builtin_bit_cast(bf16x8, pk);                            \
          acc0 = __builtin_amdgcn_mfma_f32_32x32x16_bf16(aa, bhf[(ksc)][0], acc0, 0,0,0); \
          acc1 = __builtin_amdgcn_mfma_f32_32x32x16_bf16(aa, bhf[(ksc)][1], acc1, 0,0,0); \
          done |= (1u << (ksc));                                                 \
        } } } while (0)

      #define RELOAD_MISSING do {                                                \
        _Pragma("unroll")                                                        \
        for (int ks = 0; ks < 8; ++ks) {                                         \
          if (!(done & (1u << ks))) {                                            \
            const char* a = hsrc + ((wv*8 + ks)*64 + lane)*32;                   \
            hv[ks*2]     = load_sc1_x4_issue(a);                                 \
            hv[ks*2 + 1] = load_sc1_x4_issue(a + 16);                            \
          }                                                                      \
        }                                                                        \
        fence_vm();                                                              \
        __builtin_amdgcn_sched_barrier(0);                                       \
      } while (0)

      // hit path: vmcnt retires in issue order; <=2 prior stores in flight, so
      // vmcnt(8) guarantees the first 8 loads (chunks 0-3) have landed.
      fence_vm8();
      __builtin_amdgcn_sched_barrier(0);
      VC(0); VC(1); VC(2); VC(3);
      fence_vm();
      __builtin_amdgcn_sched_barrier(0);
      VC(4); VC(5); VC(6); VC(7);

      // direct sc1 retries (authoritative): self-throttled by vmcnt(0) RT,
      // reloads ONLY stale chunks -> no load storm possible.
      if (done != 0xFFu) {
        RELOAD_MISSING;
        VC(0); VC(1); VC(2); VC(3); VC(4); VC(5); VC(6); VC(7);
      }
      if (done != 0xFFu) {
        RELOAD_MISSING;
        VC(0); VC(1); VC(2); VC(3); VC(4); VC(5); VC(6); VC(7);
      }

      // fallback: sentinel-throttled loop (liveness guarantee)
      int it = 0;
      while (done != 0xFFu) {
        if (++it > (1 << 15)) break;               // safety valve
        for (;;) {
          int v = tw;
          if (lane < 8 && !(done & (1u << lane)))
            v = load_sc1_dw_wait(hsrc + (wv*8 + lane)*2048);
          if (__all((((unsigned)(v ^ tw)) >> 16) == 0)) break;
          if (++it > (1 << 15)) break;
        }
        if (it > (1 << 15)) break;
        RELOAD_MISSING;
        VC(0); VC(1); VC(2); VC(3); VC(4); VC(5); VC(6); VC(7);
      }
      #undef RELOAD_MISSING
      #undef VC
    }

    // ---- K-split partials, double-buffered col-major [t&1][wv][col][36] ----
    {
      const int c0 = lane & 31, hi4 = (lane >> 5) << 2;
      char* pb = lds + L_PB + p*36864 + wv*9216;
      #pragma unroll
      for (int q = 0; q < 4; ++q) {
        const int r0 = q*8 + hi4;
        f32x4_t v0 = {acc0[q*4], acc0[q*4+1], acc0[q*4+2], acc0[q*4+3]};
        f32x4_t v1 = {acc1[q*4], acc1[q*4+1], acc1[q*4+2], acc1[q*4+3]};
        *(f32x4_t*)(pb + (c0*36 + r0)*4)        = v0;
        *(f32x4_t*)(pb + ((32 + c0)*36 + r0)*4) = v1;
      }
    }
    __syncthreads();   // B2 — the only barrier per step

    // ---- issue next-step embedding gather (overlaps epilogue LDS reads) ----
    i32x4 aev[4];
    if (t < TS-1) {
      #pragma unroll
      for (int i = 0; i < 4; ++i) {
        const int ck = i*64 + lane;
        const int row = ck >> 3, c8 = ck & 7;
        const int xv = xs[(t+1)*BB + bg*32 + row];
        aev[i] = *(const i32x4*)(ebuf + xv*512 + wv*128 + c8*16);
      }
    }

    // ---- fused epilogue: reduce + activations + c/h ----
    float h0, h1;
    {
      const char* pbb = lds + L_PB + p*36864;
      float a8[8];
      #pragma unroll
      for (int g = 0; g < 4; ++g) {
        f32x2_t bv = *(const f32x2_t*)(lds + L_BIAS + (g*16 + cu)*4);
        float s0 = bv[0], s1 = bv[1];
        #pragma unroll
        for (int pp = 0; pp < 4; ++pp) {
          const char* q = pbb + pp*9216 + ((g*16 + cu)*36 + e_rr)*4;
          s0 += *(const float*)(q);
          s1 += *(const float*)(q + 36*4);
        }
        a8[g*2] = s0; a8[g*2+1] = s1;
      }
      const float i0 = sigm(a8[0]),   i1 = sigm(a8[1]);
      const float f0 = sigm(a8[2]),   f1 = sigm(a8[3]);
      const float g0 = tanhf_(a8[4]), g1 = tanhf_(a8[5]);
      const float o0 = sigm(a8[6]),   o1 = sigm(a8[7]);
      cr0 = f0*cr0 + i0*g0;
      cr1 = f1*cr1 + i1*g1;
      h0 = o0 * tanhf_(cr0);
      h1 = o1 * tanhf_(cr1);
    }

    // ---- tagged h store FIRST (fire-and-forget, self-validating), then outs ----
    if (t < TS-1) {
      const int tagw = (t + 1) << 16;
      i32x2 d = { tagw | (int)f2bf(h0), tagw | (int)f2bf(h1) };
      store_sc1_x2(ws + (p^1)*HBUF_BYTES + bg*HGRP_BYTES +
                   (gt*64 + e_hi*32 + e_rr)*32 + e_jj*8, d);
    }
    {
      float* orow = out + ((size_t)t*BB + bg*32 + e_rr)*HD + gt*16 + cu;
      *(f32x2_t*)orow = (f32x2_t){h0, h1};
      if (t == TS-1) {
        float* ho = out + (size_t)TS*BB*HD + (size_t)(bg*32 + e_rr)*HD + gt*16 + cu;
        *(f32x2_t*)ho = (f32x2_t){h0, h1};
        float* cb = ho + BB*HD;
        *(f32x2_t*)cb = (f32x2_t){cr0, cr1};
      }
    }

    // ---- wave-private L_AE staging for t+1 (no barrier needed) ----
    if (t < TS-1) {
      #pragma unroll
      for (int i = 0; i < 4; ++i) {
        const int ck = i*64 + lane;
        const int row = ck >> 3, c8 = ck & 7;
        *(i32x4*)(lds + L_AE + wv*4096 + row*128 + ((c8*16) ^ ((row & 7) << 4))) = aev[i];
      }
    }
  }
}

extern "C" void kernel_launch(void* const* d_in, const int* in_sizes, int n_in,
                              void* d_out, int out_size, void* d_ws, size_t ws_size,
                              hipStream_t stream) {
  (void)in_sizes; (void)n_in; (void)out_size; (void)ws_size;
  const int*   xs  = (const int*)d_in[0];
  const float* emb = (const float*)d_in[1];
  const float* Wih = (const float*)d_in[2];
  const float* Whh = (const float*)d_in[3];
  const float* bih = (const float*)d_in[4];
  const float* bhh = (const float*)d_in[5];
  char* ws = (char*)d_ws;

  // deterministic per-call init: buf0 = h_{-1}=0 with tag 0
  (void)hipMemsetAsync(ws, 0, HBUF_BYTES, stream);
  emb2bf_kernel<<<512, 256, 0, stream>>>(emb, (unsigned short*)(ws + EBUF_OFF));
  lstm_kernel<<<256, 256, 0, stream>>>(xs, Wih, Whh, bih, bhh, ws, (float*)d_out);
}